// Round 14
// baseline (100.018 us; speedup 1.0000x reference)
//
#include <hip/hip_runtime.h>

#define NUMC 14
#define FD 128
#define SPATIAL (16*128*128)      // 262144 per batch = 2^18
#define N_TOTAL (2*SPATIAL)       // 524288
#define NV 50
#define NH 25
#define TC 13
#define QLEN 4096
#define MCH 32                    // negatives per neg-block
#define NCHUNK 64                 // 2048 / MCH
#define NSTR (FD + 4)             // 132: queue row stride in LDS (words)
#define NNEGBLK (TC * NCHUNK)     // 832
#define THRESH_F 0.3f

// k_sums geometry: one plane-chunk per block, class-major LDS accumulators
#define PXB 32768                 // pixels per block
#define CHB (SPATIAL / PXB)       // 8 chunks per plane
#define NSUMBLK (256 * CHB)       // 2048 blocks
#define NPI 64                    // partials per (class,channel)

typedef float f32x4 __attribute__((ext_vector_type(4)));

// ws offsets in 4-byte units (16B-aligned regions)
#define WS_LOSSP   0              // float[13]
#define WS_CNT0    16             // int[1]
#define WS_NEGPART 32             // float[650*64] = 41600 -> ends 41632
#define WS_ANORM   41632          // float[656] -> ends 42288 (pad 42304)
#define WS_AROWS   42304          // float[650*128] = 83200 -> ends 125504
#define WS_PART    125504         // float[14*64*128] = 114688 -> ends 240192
#define WS_LAB8    240192         // uchar[524288] = 131072 words -> ends 371264

// ------- kernel 1: label prep (blocks<512) + per-anchor select+gather (650) + init -------
__global__ __launch_bounds__(256) void k_pre(const int* __restrict__ labels,
        const int* __restrict__ predict, const float* __restrict__ prob,
        const float* __restrict__ feats, unsigned char* __restrict__ lab8,
        float* __restrict__ arows, float* __restrict__ anorm, int* __restrict__ cnt0) {
    int blk = blockIdx.x;
    int tid = threadIdx.x;
    if (blk < 512) {
        int n = blk * 1024 + tid * 4;
        int4   lb = *(const int4*)(labels + n);
        float4 pv = *(const float4*)(prob + n);
        uchar4 o;
        o.x = pv.x > THRESH_F ? (unsigned char)(lb.x & 15) : (unsigned char)15;
        o.y = pv.y > THRESH_F ? (unsigned char)(lb.y & 15) : (unsigned char)15;
        o.z = pv.z > THRESH_F ? (unsigned char)(lb.z & 15) : (unsigned char)15;
        o.w = pv.w > THRESH_F ? (unsigned char)(lb.w & 15) : (unsigned char)15;
        *(uchar4*)(lab8 + n) = o;
        if (blk == 0 && tid == 0) cnt0[0] = 0;
    } else {
        // one block per anchor row: windowed select scan (L2-hot, deterministic) + gather
        __shared__ unsigned long long masks[4];
        __shared__ int n_tgt;
        __shared__ float red[2];
        int r = blk - 512;                 // 0..649
        int ci = r / NV;                   // 0..12
        int j  = r % NV;
        bool hard = j < NH;
        int target = hard ? j : j - NH;    // rank within category
        int c = ci + 1;
        if (tid == 0) n_tgt = N_TOTAL - 1; // OOB-gather clamp default
        __syncthreads();
        int lane = tid & 63, w = tid >> 6;
        int found = 0;
        for (int base = 0; base < N_TOTAL && found <= target; base += 256) {
            int n = base + tid;
            int pr = predict[n];
            int lb = labels[n];
            float pb = prob[n];
            bool m = (pr == c) && (pb > THRESH_F) && (hard ? (lb != c) : (lb == c));
            unsigned long long mk = __ballot(m);
            if (lane == 0) masks[w] = mk;
            __syncthreads();
            int pre = 0;
            #pragma unroll
            for (int q = 0; q < 4; ++q)
                if (q < w) pre += __popcll(masks[q]);
            int rank = found + pre + __popcll(mk & ((1ull << lane) - 1ull));
            if (m && rank == target) n_tgt = n;
            found += __popcll(masks[0]) + __popcll(masks[1])
                   + __popcll(masks[2]) + __popcll(masks[3]);
            __syncthreads();
        }
        int n = n_tgt;
        if (tid < 128) {
            int b = n >> 18, sp = n & (SPATIAL - 1);
            float v = feats[((size_t)(b * FD + tid)) * SPATIAL + sp];
            arows[r * FD + tid] = v;
            float a = v * v;
            #pragma unroll
            for (int o = 32; o; o >>= 1) a += __shfl_xor(a, o);
            if ((tid & 63) == 0) red[tid >> 6] = a;
        }
        __syncthreads();
        if (tid == 0) anorm[r] = sqrtf(red[0] + red[1]);
    }
}

// ---------- kernel 2 (fused): negatives (blocks < 832) + class sums (rest) ----------
#define ACC(v, u) do { \
    acc[((u).x & 15) << 8] += (v).x; \
    acc[((u).y & 15) << 8] += (v).y; \
    acc[((u).z & 15) << 8] += (v).z; \
    acc[((u).w & 15) << 8] += (v).w; \
} while (0)

__global__ __launch_bounds__(256) void k_main(const float* __restrict__ feats,
        const unsigned char* __restrict__ lab8, const float* __restrict__ queue,
        const float* __restrict__ arows, const float* __restrict__ anorm,
        float* __restrict__ part, float* __restrict__ negpart) {
    __shared__ float smem[4352];   // 17 KB: max(neg 4274, sums 4096) words
    int tid = threadIdx.x;
    int lane = tid & 63, w = tid >> 6;

    if (blockIdx.x < NNEGBLK) {
        // ---- negatives: exp-sum partials over MCH=32 queue rows ----
        int ci = blockIdx.x >> 6;          // 0..12
        int chunk = blockIdx.x & 63;       // 0..63
        float* n_s  = smem;                // 32*132 = 4224 words
        float* an_s = smem + 4224;         // 50
        if (tid < NV) an_s[tid] = anorm[ci * NV + tid];
        const float4* qp4 = (const float4*)(queue
            + ((size_t)(ci + 1) * QLEN + (QLEN / 2) + chunk * MCH) * (size_t)FD);
        for (int i = tid; i < MCH * (FD / 4); i += 256) {
            int m = i >> 5, k4 = i & 31;
            ((float4*)(n_s + m * NSTR))[k4] = qp4[i];
        }
        __syncthreads();
        int half = lane >> 5, l32 = lane & 31;
        const float4* nrow = (const float4*)(n_s + l32 * NSTR);   // lane&31 owns row
        float sq = 0.f;
        #pragma unroll
        for (int k = 0; k < FD / 4; ++k) {
            float4 t = nrow[k];
            sq += t.x*t.x + t.y*t.y + t.z*t.z + t.w*t.w;
        }
        float inn = 10.f * rsqrtf(sq);   // 1/TEMP folded in
        float* np = negpart + (size_t)(ci * NV) * NCHUNK + chunk;   // [row][chunk]
        const float4* abase = (const float4*)(arows + (size_t)(ci * NV) * FD);
        for (int v = w * 2 + half; v < NV; v += 8) {   // 2 anchors per wave
            const float4* a4 = abase + v * (FD / 4);   // per-half-wave uniform
            float dot = 0.f;
            #pragma unroll
            for (int k = 0; k < FD / 4; ++k) {
                float4 x = a4[k], y = nrow[k];
                dot += x.x*y.x + x.y*y.y + x.z*y.z + x.w*y.w;
            }
            float e = __expf(dot * inn / an_s[v]);
            #pragma unroll
            for (int o = 16; o; o >>= 1) e += __shfl_xor(e, o);   // within 32-lane half
            if (l32 == 0) np[(size_t)v * NCHUNK] = e;
        }
    } else {
        // ---- class sums: class-major conflict-free LDS + 4-deep prefetch ----
        // addr = (lab&15)*256 + tid -> bank = tid%32, label-independent, 2 lanes/bank.
        int sb = blockIdx.x - NNEGBLK;      // 0..2047
        int plane = sb >> 3;                // 0..255 = b*128 + ch
        int chunk = sb & (CHB - 1);         // 0..7
        int b = plane >> 7;
        int ch = plane & 127;
        float* acc = smem + tid;            // slot for class c at acc[c<<8]
        #pragma unroll
        for (int c = 0; c < 16; ++c) acc[c << 8] = 0.f;

        const f32x4*  fp4 = (const f32x4*)(feats + (size_t)plane * SPATIAL) + (chunk << 13);
        const uchar4* lp4 = (const uchar4*)(lab8 + (size_t)b * SPATIAL) + (chunk << 13);
        f32x4  v0 = fp4[tid],       v1 = fp4[tid + 256];
        f32x4  v2 = fp4[tid + 512], v3 = fp4[tid + 768];
        uchar4 u0 = lp4[tid],       u1 = lp4[tid + 256];
        uchar4 u2 = lp4[tid + 512], u3 = lp4[tid + 768];
        for (int i = 0; i < 28; i += 4) {
            f32x4  p0 = fp4[(i + 4) * 256 + tid];
            uchar4 q0 = lp4[(i + 4) * 256 + tid];
            ACC(v0, u0);
            f32x4  p1 = fp4[(i + 5) * 256 + tid];
            uchar4 q1 = lp4[(i + 5) * 256 + tid];
            ACC(v1, u1);
            f32x4  p2 = fp4[(i + 6) * 256 + tid];
            uchar4 q2 = lp4[(i + 6) * 256 + tid];
            ACC(v2, u2);
            f32x4  p3 = fp4[(i + 7) * 256 + tid];
            uchar4 q3 = lp4[(i + 7) * 256 + tid];
            ACC(v3, u3);
            v0 = p0; u0 = q0; v1 = p1; u1 = q1;
            v2 = p2; u2 = q2; v3 = p3; u3 = q3;
        }
        ACC(v0, u0); ACC(v1, u1); ACC(v2, u2); ACC(v3, u3);

        // shuffle-only epilogue (reads own slots, no barrier);
        // part layout [class][pi][ch] -> k_loss reads coalesced
        int pi = b * 32 + chunk * 4 + w;    // 0..63
        #pragma unroll
        for (int c = 0; c < NUMC; ++c) {
            float x = acc[c << 8];
            #pragma unroll
            for (int o = 32; o; o >>= 1) x += __shfl_xor(x, o);
            if (lane == 0) part[((size_t)c * NPI + pi) * FD + ch] = x;
        }
    }
}

// ---------------- kernel 3: per-class loss + deterministic final reduce ----------------
__global__ __launch_bounds__(256) void k_loss(const float* __restrict__ arows,
        const float* __restrict__ anorm, const float* __restrict__ part,
        const float* __restrict__ negpart, float* __restrict__ lossp,
        int* __restrict__ cnt0, float* __restrict__ out) {
    __shared__ float p_s[FD];
    __shared__ float red_s[2];
    __shared__ float lacc[8];
    int tid = threadIdx.x;
    int ci = blockIdx.x, c = ci + 1;
    // class-sum reduce over NPI partials per channel (cnt cancels under l2n)
    if (tid < 128) {
        const float* pp = part + (size_t)c * NPI * FD + tid;
        float s = 0.f;
        #pragma unroll 8
        for (int k = 0; k < NPI; ++k) s += pp[(size_t)k * FD];   // coalesced per k
        p_s[tid] = s;
    }
    __syncthreads();
    if (tid < 128) {
        float q = p_s[tid] * p_s[tid];
        #pragma unroll
        for (int o = 32; o; o >>= 1) q += __shfl_xor(q, o);
        if ((tid & 63) == 0) red_s[tid >> 6] = q;
    }
    __syncthreads();
    float pninv10 = 10.f * rsqrtf(red_s[0] + red_s[1]);   // 1/(||psum|| * TEMP)
    int grp = tid >> 5, l32 = tid & 31;
    float acc = 0.f;
    for (int r = grp; r < NV; r += 8) {
        int ar = ci * NV + r;
        const float4* a4 = (const float4*)(arows + (size_t)ar * FD);
        const float4* p4 = (const float4*)p_s;
        float4 x = a4[l32], y = p4[l32];
        float d = x.x*y.x + x.y*y.y + x.z*y.z + x.w*y.w;
        float ns = negpart[(size_t)ar * NCHUNK + l32]
                 + negpart[(size_t)ar * NCHUNK + 32 + l32];
        #pragma unroll
        for (int o = 16; o; o >>= 1) { d += __shfl_xor(d, o); ns += __shfl_xor(ns, o); }
        if (l32 == 0) {
            float logit = d * pninv10 / anorm[ar];
            acc += -logit + logf(__expf(logit) + ns);
        }
    }
    if (l32 == 0) lacc[grp] = acc;
    __syncthreads();
    if (tid == 0) {
        float s = 0.f;
        #pragma unroll
        for (int i = 0; i < 8; ++i) s += lacc[i];
        lossp[ci] = s;
        __threadfence();
        int t = atomicAdd(cnt0, 1);
        if (t == TC - 1) {                  // last block: deterministic-order final sum
            __threadfence();
            float tot = 0.f;
            for (int i = 0; i < TC; ++i)
                tot += __hip_atomic_load(lossp + i, __ATOMIC_RELAXED, __HIP_MEMORY_SCOPE_AGENT);
            out[0] = tot * (1.f / (TC * NV));
        }
    }
}

extern "C" void kernel_launch(void* const* d_in, const int* in_sizes, int n_in,
                              void* d_out, int out_size, void* d_ws, size_t ws_size,
                              hipStream_t stream) {
    (void)in_sizes; (void)n_in; (void)out_size; (void)ws_size;
    const float* feats   = (const float*)d_in[0];
    const int*   labels  = (const int*)d_in[1];
    const int*   predict = (const int*)d_in[2];
    const float* prob    = (const float*)d_in[3];
    const float* queue   = (const float*)d_in[4];
    float* ws  = (float*)d_ws;
    float* out = (float*)d_out;

    float* lossp   = ws + WS_LOSSP;
    int*   cnt0    = (int*)(ws + WS_CNT0);
    float* negpart = ws + WS_NEGPART;
    float* anorm   = ws + WS_ANORM;
    float* arows   = ws + WS_AROWS;
    float* part    = ws + WS_PART;
    unsigned char* lab8 = (unsigned char*)(ws + WS_LAB8);

    k_pre  <<<512 + TC * NV, 256, 0, stream>>>(labels, predict, prob, feats,
                                               lab8, arows, anorm, cnt0);
    k_main <<<NNEGBLK + NSUMBLK, 256, 0, stream>>>(feats, lab8, queue, arows, anorm,
                                                   part, negpart);
    k_loss <<<TC, 256, 0, stream>>>(arows, anorm, part, negpart, lossp, cnt0, out);
}

// Round 15
// 96.744 us; speedup vs baseline: 1.0339x; 1.0339x over previous
//
#include <hip/hip_runtime.h>

#define NUMC 14
#define FD 128
#define SPATIAL (16*128*128)      // 262144 per batch = 2^18
#define N_TOTAL (2*SPATIAL)       // 524288
#define NV 50
#define NH 25
#define TC 13
#define QLEN 4096
#define MCH 32                    // negatives per neg-block
#define NCHUNK 64                 // 2048 / MCH
#define NSTR (FD + 4)             // 132: queue row stride in LDS (words)
#define NNEGBLK (TC * NCHUNK)     // 832
#define THRESH_F 0.3f

// k_sums geometry: one plane-chunk per block, class-major LDS accumulators
#define PXB 32768                 // pixels per block
#define CHB (SPATIAL / PXB)       // 8 chunks per plane
#define NSUMBLK (256 * CHB)       // 2048 blocks
#define NPI 64                    // partials per (class,channel)
// grid interleave: 64 groups x 45 blocks = 13 neg + 32 sums each
#define GRPSZ 45
#define NGRP 64

typedef float f32x4 __attribute__((ext_vector_type(4)));

// ws offsets in 4-byte units (16B-aligned regions)
#define WS_LOSSP   0              // float[13]
#define WS_CNT0    16             // int[1]
#define WS_NEGPART 32             // float[650*64] = 41600 -> ends 41632
#define WS_ANORM   41632          // float[656] -> ends 42288 (pad 42304)
#define WS_AROWS   42304          // float[650*128] = 83200 -> ends 125504
#define WS_PART    125504         // float[14*64*128] = 114688 -> ends 240192
#define WS_LAB8    240192         // uchar[524288] = 131072 words -> ends 371264

// ------- kernel 1: label prep (blocks<512) + per-anchor select+gather (650) + init -------
// lab8 stores class*4 (pre-scaled for LDS addressing); invalid = 60.
__global__ __launch_bounds__(256) void k_pre(const int* __restrict__ labels,
        const int* __restrict__ predict, const float* __restrict__ prob,
        const float* __restrict__ feats, unsigned char* __restrict__ lab8,
        float* __restrict__ arows, float* __restrict__ anorm, int* __restrict__ cnt0) {
    int blk = blockIdx.x;
    int tid = threadIdx.x;
    if (blk < 512) {
        int n = blk * 1024 + tid * 4;
        int4   lb = *(const int4*)(labels + n);
        float4 pv = *(const float4*)(prob + n);
        uchar4 o;
        o.x = pv.x > THRESH_F ? (unsigned char)((lb.x & 15) << 2) : (unsigned char)60;
        o.y = pv.y > THRESH_F ? (unsigned char)((lb.y & 15) << 2) : (unsigned char)60;
        o.z = pv.z > THRESH_F ? (unsigned char)((lb.z & 15) << 2) : (unsigned char)60;
        o.w = pv.w > THRESH_F ? (unsigned char)((lb.w & 15) << 2) : (unsigned char)60;
        *(uchar4*)(lab8 + n) = o;
        if (blk == 0 && tid == 0) cnt0[0] = 0;
    } else {
        // one block per anchor row: windowed select scan (L2-hot, deterministic) + gather
        __shared__ unsigned long long masks[4];
        __shared__ int n_tgt;
        __shared__ float red[2];
        int r = blk - 512;                 // 0..649
        int ci = r / NV;                   // 0..12
        int j  = r % NV;
        bool hard = j < NH;
        int target = hard ? j : j - NH;    // rank within category
        int c = ci + 1;
        if (tid == 0) n_tgt = N_TOTAL - 1; // OOB-gather clamp default
        __syncthreads();
        int lane = tid & 63, w = tid >> 6;
        int found = 0;
        for (int base = 0; base < N_TOTAL && found <= target; base += 256) {
            int n = base + tid;
            int pr = predict[n];
            int lb = labels[n];
            float pb = prob[n];
            bool m = (pr == c) && (pb > THRESH_F) && (hard ? (lb != c) : (lb == c));
            unsigned long long mk = __ballot(m);
            if (lane == 0) masks[w] = mk;
            __syncthreads();
            int pre = 0;
            #pragma unroll
            for (int q = 0; q < 4; ++q)
                if (q < w) pre += __popcll(masks[q]);
            int rank = found + pre + __popcll(mk & ((1ull << lane) - 1ull));
            if (m && rank == target) n_tgt = n;
            found += __popcll(masks[0]) + __popcll(masks[1])
                   + __popcll(masks[2]) + __popcll(masks[3]);
            __syncthreads();
        }
        int n = n_tgt;
        if (tid < 128) {
            int b = n >> 18, sp = n & (SPATIAL - 1);
            float v = feats[((size_t)(b * FD + tid)) * SPATIAL + sp];
            arows[r * FD + tid] = v;
            float a = v * v;
            #pragma unroll
            for (int o = 32; o; o >>= 1) a += __shfl_xor(a, o);
            if ((tid & 63) == 0) red[tid >> 6] = a;
        }
        __syncthreads();
        if (tid == 0) anorm[r] = sqrtf(red[0] + red[1]);
    }
}

// ---------- kernel 2 (fused, interleaved): negatives + class sums ----------
__global__ __launch_bounds__(256) void k_main(const float* __restrict__ feats,
        const unsigned char* __restrict__ lab8, const float* __restrict__ queue,
        const float* __restrict__ arows, const float* __restrict__ anorm,
        float* __restrict__ part, float* __restrict__ negpart) {
    __shared__ float smem[4352];   // 17 KB: max(neg 4274, sums 4096) words
    int tid = threadIdx.x;
    int lane = tid & 63, w = tid >> 6;
    int g = blockIdx.x / GRPSZ;         // 0..63
    int l = blockIdx.x % GRPSZ;         // 0..44

    if (l < 13) {
        // ---- negatives: exp-sum partials over MCH=32 queue rows ----
        int nb = g * 13 + l;               // 0..831
        int ci = nb >> 6;                  // 0..12
        int chunk = nb & 63;               // 0..63
        float* n_s  = smem;                // 32*132 = 4224 words
        float* an_s = smem + 4224;         // 50
        if (tid < NV) an_s[tid] = anorm[ci * NV + tid];
        const float4* qp4 = (const float4*)(queue
            + ((size_t)(ci + 1) * QLEN + (QLEN / 2) + chunk * MCH) * (size_t)FD);
        for (int i = tid; i < MCH * (FD / 4); i += 256) {
            int m = i >> 5, k4 = i & 31;
            ((float4*)(n_s + m * NSTR))[k4] = qp4[i];
        }
        __syncthreads();
        int half = lane >> 5, l32 = lane & 31;
        const float4* nrow = (const float4*)(n_s + l32 * NSTR);   // lane&31 owns row
        float sq = 0.f;
        #pragma unroll
        for (int k = 0; k < FD / 4; ++k) {
            float4 t = nrow[k];
            sq += t.x*t.x + t.y*t.y + t.z*t.z + t.w*t.w;
        }
        float inn = 10.f * rsqrtf(sq);   // 1/TEMP folded in
        float* np = negpart + (size_t)(ci * NV) * NCHUNK + chunk;   // [row][chunk]
        const float4* abase = (const float4*)(arows + (size_t)(ci * NV) * FD);
        for (int v = w * 2 + half; v < NV; v += 8) {   // 2 anchors per wave
            const float4* a4 = abase + v * (FD / 4);   // per-half-wave uniform
            float dot = 0.f;
            #pragma unroll
            for (int k = 0; k < FD / 4; ++k) {
                float4 x = a4[k], y = nrow[k];
                dot += x.x*y.x + x.y*y.y + x.z*y.z + x.w*y.w;
            }
            float e = __expf(dot * inn / an_s[v]);
            #pragma unroll
            for (int o = 16; o; o >>= 1) e += __shfl_xor(e, o);   // within 32-lane half
            if (l32 == 0) np[(size_t)v * NCHUNK] = e;
        }
    } else {
        // ---- class sums: class-major conflict-free LDS, pre-scaled labels ----
        // word addr = (u<<6) + tid : bank = tid%32, label-independent, 2 lanes/bank.
        int sb = g * 32 + (l - 13);         // 0..2047
        int plane = sb >> 3;                // 0..255 = b*128 + ch
        int chunk = sb & (CHB - 1);         // 0..7
        int b = plane >> 7;
        int ch = plane & 127;
        float* acc = smem + tid;            // slot for class c at acc[c<<8]
        #pragma unroll
        for (int c = 0; c < 16; ++c) acc[c << 8] = 0.f;

        const f32x4*  fp4 = (const f32x4*)(feats + (size_t)plane * SPATIAL) + (chunk << 13);
        const uchar4* lp4 = (const uchar4*)(lab8 + (size_t)b * SPATIAL) + (chunk << 13);
        f32x4  v = fp4[tid];
        uchar4 u = lp4[tid];
        for (int i = 0; i < 31; ++i) {
            f32x4  vn = fp4[(i + 1) * 256 + tid];
            uchar4 un = lp4[(i + 1) * 256 + tid];
            acc[u.x << 6] += v.x;           // u = class*4 -> word off class*256
            acc[u.y << 6] += v.y;
            acc[u.z << 6] += v.z;
            acc[u.w << 6] += v.w;
            v = vn; u = un;
        }
        acc[u.x << 6] += v.x;
        acc[u.y << 6] += v.y;
        acc[u.z << 6] += v.z;
        acc[u.w << 6] += v.w;

        // shuffle-only epilogue (reads own slots, no barrier);
        // part layout [class][pi][ch] -> k_loss reads coalesced
        int pi = b * 32 + chunk * 4 + w;    // 0..63
        #pragma unroll
        for (int c = 0; c < NUMC; ++c) {
            float x = acc[c << 8];
            #pragma unroll
            for (int o = 32; o; o >>= 1) x += __shfl_xor(x, o);
            if (lane == 0) part[((size_t)c * NPI + pi) * FD + ch] = x;
        }
    }
}

// ---------------- kernel 3: per-class loss + deterministic final reduce ----------------
__global__ __launch_bounds__(256) void k_loss(const float* __restrict__ arows,
        const float* __restrict__ anorm, const float* __restrict__ part,
        const float* __restrict__ negpart, float* __restrict__ lossp,
        int* __restrict__ cnt0, float* __restrict__ out) {
    __shared__ float p_s[FD];
    __shared__ float red_s[2];
    __shared__ float lacc[8];
    int tid = threadIdx.x;
    int ci = blockIdx.x, c = ci + 1;
    // class-sum reduce over NPI partials per channel (cnt cancels under l2n)
    if (tid < 128) {
        const float* pp = part + (size_t)c * NPI * FD + tid;
        float s = 0.f;
        #pragma unroll 16
        for (int k = 0; k < NPI; ++k) s += pp[(size_t)k * FD];   // coalesced per k
        p_s[tid] = s;
    }
    __syncthreads();
    if (tid < 128) {
        float q = p_s[tid] * p_s[tid];
        #pragma unroll
        for (int o = 32; o; o >>= 1) q += __shfl_xor(q, o);
        if ((tid & 63) == 0) red_s[tid >> 6] = q;
    }
    __syncthreads();
    float pninv10 = 10.f * rsqrtf(red_s[0] + red_s[1]);   // 1/(||psum|| * TEMP)
    int grp = tid >> 5, l32 = tid & 31;
    float acc = 0.f;
    for (int r = grp; r < NV; r += 8) {
        int ar = ci * NV + r;
        const float4* a4 = (const float4*)(arows + (size_t)ar * FD);
        const float4* p4 = (const float4*)p_s;
        float4 x = a4[l32], y = p4[l32];
        float d = x.x*y.x + x.y*y.y + x.z*y.z + x.w*y.w;
        float ns = negpart[(size_t)ar * NCHUNK + l32]
                 + negpart[(size_t)ar * NCHUNK + 32 + l32];
        #pragma unroll
        for (int o = 16; o; o >>= 1) { d += __shfl_xor(d, o); ns += __shfl_xor(ns, o); }
        if (l32 == 0) {
            float logit = d * pninv10 / anorm[ar];
            acc += -logit + logf(__expf(logit) + ns);
        }
    }
    if (l32 == 0) lacc[grp] = acc;
    __syncthreads();
    if (tid == 0) {
        float s = 0.f;
        #pragma unroll
        for (int i = 0; i < 8; ++i) s += lacc[i];
        lossp[ci] = s;
        __threadfence();
        int t = atomicAdd(cnt0, 1);
        if (t == TC - 1) {                  // last block: deterministic-order final sum
            __threadfence();
            float tot = 0.f;
            for (int i = 0; i < TC; ++i)
                tot += __hip_atomic_load(lossp + i, __ATOMIC_RELAXED, __HIP_MEMORY_SCOPE_AGENT);
            out[0] = tot * (1.f / (TC * NV));
        }
    }
}

extern "C" void kernel_launch(void* const* d_in, const int* in_sizes, int n_in,
                              void* d_out, int out_size, void* d_ws, size_t ws_size,
                              hipStream_t stream) {
    (void)in_sizes; (void)n_in; (void)out_size; (void)ws_size;
    const float* feats   = (const float*)d_in[0];
    const int*   labels  = (const int*)d_in[1];
    const int*   predict = (const int*)d_in[2];
    const float* prob    = (const float*)d_in[3];
    const float* queue   = (const float*)d_in[4];
    float* ws  = (float*)d_ws;
    float* out = (float*)d_out;

    float* lossp   = ws + WS_LOSSP;
    int*   cnt0    = (int*)(ws + WS_CNT0);
    float* negpart = ws + WS_NEGPART;
    float* anorm   = ws + WS_ANORM;
    float* arows   = ws + WS_AROWS;
    float* part    = ws + WS_PART;
    unsigned char* lab8 = (unsigned char*)(ws + WS_LAB8);

    k_pre  <<<512 + TC * NV, 256, 0, stream>>>(labels, predict, prob, feats,
                                               lab8, arows, anorm, cnt0);
    k_main <<<NGRP * GRPSZ, 256, 0, stream>>>(feats, lab8, queue, arows, anorm,
                                              part, negpart);
    k_loss <<<TC, 256, 0, stream>>>(arows, anorm, part, negpart, lossp, cnt0, out);
}